// Round 7
// baseline (149.273 us; speedup 1.0000x reference)
//
#include <hip/hip_runtime.h>

#define FFT_N 8192
#define BT    1024
#define D_IN  2048
#define PI2   6.28318530717958647692f

typedef float    f32x2 __attribute__((ext_vector_type(2)));
typedef _Float16 f16x2 __attribute__((ext_vector_type(2)));

__device__ __forceinline__ int P(int i) { return i + (i >> 5); }

// ---- packed-fp16 LDS helpers (compute stays fp32 in regs) ----
__device__ __forceinline__ f32x2 ldH(const unsigned* p) {
    f16x2 h = __builtin_bit_cast(f16x2, *p);
    return (f32x2){(float)h.x, (float)h.y};
}
__device__ __forceinline__ unsigned packH(f32x2 v) {
    f16x2 h = { (_Float16)v.x, (_Float16)v.y };
    return __builtin_bit_cast(unsigned, h);
}
template<int HI>
__device__ __forceinline__ void atomAddH(unsigned* p, float val) {
    unsigned old = *p;
    while (true) {
        f16x2 h = __builtin_bit_cast(f16x2, old);
        if (HI) h.y += (_Float16)val; else h.x += (_Float16)val;
        unsigned nv = __builtin_bit_cast(unsigned, h);
        unsigned got = atomicCAS(p, old, nv);
        if (got == old) break;
        old = got;
    }
}

__device__ __forceinline__ f32x2 cmul(f32x2 a, f32x2 b) {
    f32x2 q = (f32x2){-a.y, a.y} * (f32x2){b.y, b.x};
    return (f32x2){a.x, a.x} * b + q;
}

// 8-point DFT, natural in -> natural out, kernel e^{S*2pi*i*ru/8}, unnormalized.
template<int S>
__device__ __forceinline__ void fft8(f32x2* v) {
    const float C2 = 0.707106781186547524f;   // cos(pi/4)
    const float Sf = (float)S;
    f32x2 t;
#define SW(a,b) t = v[a]; v[a] = v[b]; v[b] = t;
    SW(1,4) SW(3,6)
#undef SW
#define BF(i0,i1,WR,WI) { f32x2 tt = cmul(v[i1], (f32x2){(WR),(WI)}); \
    f32x2 a0 = v[i0]; v[i0] = a0 + tt; v[i1] = a0 - tt; }
#define BF1(i0,i1) { f32x2 tt = v[i1]; \
    f32x2 a0 = v[i0]; v[i0] = a0 + tt; v[i1] = a0 - tt; }
#define BFI(i0,i1) { f32x2 b1 = v[i1]; f32x2 tt = (f32x2){-Sf * b1.y, Sf * b1.x}; \
    f32x2 a0 = v[i0]; v[i0] = a0 + tt; v[i1] = a0 - tt; }
    BF1(0,1) BF1(2,3) BF1(4,5) BF1(6,7)
    BF1(0,2) BFI(1,3) BF1(4,6) BFI(5,7)
    BF1(0,4) BF(1,5,C2,Sf*C2) BFI(2,6) BF(3,7,-C2,Sf*C2)
#undef BF
#undef BF1
#undef BFI
}

// v[u] *= w1^u, u=1..7 — serial chain, 2 live regs
__device__ __forceinline__ void twiddle8_w(f32x2* v, f32x2 w1) {
    f32x2 w = w1;
    v[1] = cmul(v[1], w);
    #pragma unroll
    for (int u = 2; u < 8; ++u) { w = cmul(w, w1); v[u] = cmul(v[u], w); }
}
__device__ __forceinline__ void twiddle8(f32x2* v, float ang) {
    float sn, cs;
    __sincosf(ang, &sn, &cs);
    twiddle8_w(v, (f32x2){cs, sn});
}

__global__ __launch_bounds__(BT, 8)   // 8 waves/EU -> VGPR cap 64; 2 blocks/CU
void cbp_fused_kernel(const float* __restrict__ x, const float* __restrict__ y,
                      const int* __restrict__ h1, const int* __restrict__ h2,
                      const float* __restrict__ s1, const float* __restrict__ s2,
                      float* __restrict__ out) {
    __shared__ unsigned hz[8448];      // half2-packed complex, pad i+(i>>5); 33792 B
    const int tid = threadIdx.x;
    const int b   = blockIdx.x;

    // hoisted global loads (2 elements each; hide under zero phase)
    float2 xv  = ((const float2*)(x + (size_t)b * D_IN))[tid];
    float2 yv  = ((const float2*)(y + (size_t)b * D_IN))[tid];
    int2   h1v = ((const int2*)h1)[tid];
    int2   h2v = ((const int2*)h2)[tid];
    float2 s1v = ((const float2*)s1)[tid];
    float2 s2v = ((const float2*)s2)[tid];

    // ---- zero ALL 2112 uint4 slots (bug fix: previous version missed [2048,2112)) ----
    {
        uint4* z4 = (uint4*)hz;
        z4[tid]        = (uint4){0u, 0u, 0u, 0u};
        z4[tid + 1024] = (uint4){0u, 0u, 0u, 0u};
        if (tid < 64) z4[tid + 2048] = (uint4){0u, 0u, 0u, 0u};
    }
    __syncthreads();

    // ---- count sketch: z = xs + i*ys (fp16 CAS adds) ----
    atomAddH<0>(&hz[P(h1v.x)], xv.x * s1v.x);
    atomAddH<0>(&hz[P(h1v.y)], xv.y * s1v.y);
    atomAddH<1>(&hz[P(h2v.x)], yv.x * s2v.x);
    atomAddH<1>(&hz[P(h2v.y)], yv.y * s2v.y);
    __syncthreads();

    f32x2 v[8];
    const int g2 = tid >> 7, m2 = tid & 127;   // stage-2 digits
    const int g3 = tid >> 4, m3 = tid & 15;    // stage-3 digits
    const int g4 = tid >> 1, m4 = tid & 1;     // stage-4 digits
    // stage-3 padded offsets for logical stride 16: 33*(r>>1) + 16*(r&1)
    const int OFF3[8] = {0, 16, 33, 49, 66, 82, 99, 115};

    // ---- fwd S1: radix-8, stride 1024 (padded 1056) ----
    {
        unsigned* zp = &hz[P(tid)];
        #pragma unroll
        for (int r = 0; r < 8; ++r) v[r] = ldH(zp + 1056 * r);
        fft8<-1>(v);
        twiddle8(v, (float)tid * (-PI2 / 8192.f));
        #pragma unroll
        for (int u = 0; u < 8; ++u) zp[1056 * u] = packH(v[u]);
    }
    __syncthreads();

    // ---- fwd S2: radix-8, stride 128 (padded 132) ----
    {
        unsigned* zp = &hz[P(g2 * 1024 + m2)];
        #pragma unroll
        for (int r = 0; r < 8; ++r) v[r] = ldH(zp + 132 * r);
        fft8<-1>(v);
        twiddle8(v, (float)m2 * (-PI2 / 1024.f));
        #pragma unroll
        for (int u = 0; u < 8; ++u) zp[132 * u] = packH(v[u]);
    }
    __syncthreads();

    // ---- fwd S3: radix-8, stride 16 (padded offsets OFF3) ----
    {
        unsigned* zp = &hz[P(g3 * 128 + m3)];
        #pragma unroll
        for (int r = 0; r < 8; ++r) v[r] = ldH(zp + OFF3[r]);
        fft8<-1>(v);
        twiddle8(v, (float)m3 * (-PI2 / 128.f));
        #pragma unroll
        for (int u = 0; u < 8; ++u) zp[OFF3[u]] = packH(v[u]);
    }
    __syncthreads();

    // ---- fwd S4: radix-8, stride 2 + radix-2 via lane-pair shfl ----
    // subproblem length is 16 -> inter-stage twiddle w1 = e^{-2pi*i*m4/16}
    unsigned* z4p = &hz[P(g4 * 16 + m4)];
    {
        #pragma unroll
        for (int r = 0; r < 8; ++r) v[r] = ldH(z4p + 2 * r);
        fft8<-1>(v);
        f32x2 w1f = m4 ? (f32x2){0.923879532511286756f, -0.382683432365089772f}
                       : (f32x2){1.f, 0.f};
        twiddle8_w(v, w1f);
        const float sgn = m4 ? -1.f : 1.f;
        #pragma unroll
        for (int u = 0; u < 8; ++u) {
            float px = __shfl_xor(v[u].x, 1);
            float py = __shfl_xor(v[u].y, 1);
            v[u] = (f32x2){fmaf(sgn, v[u].x, px), fmaf(sgn, v[u].y, py)};
        }
        #pragma unroll
        for (int u = 0; u < 8; ++u) z4p[2 * u] = packH(v[u]);   // publish for partners
    }
    __syncthreads();

    // ---- Hermitian split + pointwise product, in registers ----
    // v[r] holds k = K0 + 512 r, K0 = rev8(g4) + 4096*m4 (rev8 = 3-digit octal reverse)
    {
        const int K0 = (((g4 & 7) << 6) | (g4 & 56) | (g4 >> 6)) | (m4 << 12);
        const int e  = (FFT_N - K0) & 511;
        const int C  = (FFT_N - K0 - e) >> 9;
        const int cp = ((e & 7) << 6) | (e & 56) | (e >> 6);
        const unsigned* zb = &hz[P(cp * 16)];
        #pragma unroll
        for (int r = 0; r < 8; ++r) {
            const int q = C - r;
            f32x2 z2 = ldH(zb + 2 * (q & 7) + (q >> 3));
            if (r == 0) { if (K0 == 0) z2 = v[0]; }   // k=0 singleton (tid 0 only)
            f32x2 X = v[r] + (f32x2){ z2.x, -z2.y};               // (2ReX, 2ImX)
            f32x2 Y = (f32x2){v[r].y, -v[r].x} + (f32x2){z2.y, z2.x};  // (2ReY, 2ImY)
            v[r] = cmul(X, Y);                                    // 4*X*Y
        }
    }

    // ---- inverse A (regs): radix-2 shfl, conj twiddle (e^{+2pi*i*m4/16}), fft8<+1> ----
    {
        const float sgn = m4 ? -1.f : 1.f;
        #pragma unroll
        for (int u = 0; u < 8; ++u) {
            float px = __shfl_xor(v[u].x, 1);
            float py = __shfl_xor(v[u].y, 1);
            v[u] = (f32x2){fmaf(sgn, v[u].x, px), fmaf(sgn, v[u].y, py)};
        }
        f32x2 w1i = m4 ? (f32x2){0.923879532511286756f, 0.382683432365089772f}
                       : (f32x2){1.f, 0.f};
        twiddle8_w(v, w1i);
        fft8<1>(v);
    }
    __syncthreads();                   // all partner reads done before overwrite
    {
        #pragma unroll
        for (int r = 0; r < 8; ++r) z4p[2 * r] = packH(v[r] * 0.03125f);   // *2^-5
    }
    __syncthreads();

    // ---- inverse I3: stride 16 ----
    {
        unsigned* zp = &hz[P(g3 * 128 + m3)];
        #pragma unroll
        for (int u = 0; u < 8; ++u) v[u] = ldH(zp + OFF3[u]);
        twiddle8(v, (float)m3 * (PI2 / 128.f));
        fft8<1>(v);
        #pragma unroll
        for (int r = 0; r < 8; ++r) zp[OFF3[r]] = packH(v[r] * 0.03125f);  // *2^-5
    }
    __syncthreads();

    // ---- inverse I2: stride 128 ----
    {
        unsigned* zp = &hz[P(g2 * 1024 + m2)];
        #pragma unroll
        for (int u = 0; u < 8; ++u) v[u] = ldH(zp + 132 * u);
        twiddle8(v, (float)m2 * (PI2 / 1024.f));
        fft8<1>(v);
        #pragma unroll
        for (int r = 0; r < 8; ++r) zp[132 * r] = packH(v[r] * 0.03125f);  // *2^-5
    }
    __syncthreads();

    // ---- inverse I1: stride 1024 + coalesced global write of real part ----
    {
        unsigned* zp = &hz[P(tid)];
        #pragma unroll
        for (int u = 0; u < 8; ++u) v[u] = ldH(zp + 1056 * u);
        twiddle8(v, (float)tid * (PI2 / 8192.f));
        fft8<1>(v);
        float* orow = out + (size_t)b * FFT_N;
        // total scale already applied: (2^-5)^3 = 1/(4*8192)
        #pragma unroll
        for (int r = 0; r < 8; ++r) orow[tid + (r << 10)] = v[r].x;
    }
}

extern "C" void kernel_launch(void* const* d_in, const int* in_sizes, int n_in,
                              void* d_out, int out_size, void* d_ws, size_t ws_size,
                              hipStream_t stream) {
    const float* x  = (const float*)d_in[0];
    const float* y  = (const float*)d_in[1];
    const int*   h1 = (const int*)d_in[2];
    const int*   h2 = (const int*)d_in[3];
    const float* s1 = (const float*)d_in[4];
    const float* s2 = (const float*)d_in[5];
    float* out = (float*)d_out;

    const int B = in_sizes[0] / D_IN;   // 4096 rows
    cbp_fused_kernel<<<B, BT, 0, stream>>>(x, y, h1, h2, s1, s2, out);
}

// Round 8
// 134.065 us; speedup vs baseline: 1.1134x; 1.1134x over previous
//
#include <hip/hip_runtime.h>

#define FFT_N 8192
#define BT    512
#define D_IN  2048
#define PI2   6.28318530717958647692f

typedef float    f32x2 __attribute__((ext_vector_type(2)));
typedef _Float16 f16x2 __attribute__((ext_vector_type(2)));

// ---- packed-fp16 LDS helpers (compute stays fp32 in regs) ----
__device__ __forceinline__ f32x2 ldH(const unsigned* p) {
    f16x2 h = __builtin_bit_cast(f16x2, *p);
    return (f32x2){(float)h.x, (float)h.y};
}
__device__ __forceinline__ unsigned packH(f32x2 v) {
    f16x2 h = { (_Float16)v.x, (_Float16)v.y };
    return __builtin_bit_cast(unsigned, h);
}
template<int HI>
__device__ __forceinline__ void atomAddH(unsigned* p, float val) {
    unsigned old = *p;
    while (true) {
        f16x2 h = __builtin_bit_cast(f16x2, old);
        if (HI) h.y += (_Float16)val; else h.x += (_Float16)val;
        unsigned nv = __builtin_bit_cast(unsigned, h);
        unsigned got = atomicCAS(p, old, nv);
        if (got == old) break;
        old = got;
    }
}

__device__ __forceinline__ f32x2 cmul(f32x2 a, f32x2 b) {
    f32x2 q = (f32x2){-a.y, a.y} * (f32x2){b.y, b.x};
    return (f32x2){a.x, a.x} * b + q;
}

// 16-point DFT, natural in -> natural out, kernel e^{S*2pi*i*ru/16}, unnormalized.
template<int S>
__device__ __forceinline__ void fft16(f32x2* v) {
    const float C1 = 0.923879532511286756f;   // cos(pi/8)
    const float C2 = 0.707106781186547524f;   // cos(pi/4)
    const float C3 = 0.382683432365089772f;   // sin(pi/8)
    const float Sf = (float)S;
    f32x2 t;
#define SW(a,b) t = v[a]; v[a] = v[b]; v[b] = t;
    SW(1,8) SW(2,4) SW(3,12) SW(5,10) SW(7,14) SW(11,13)
#undef SW
#define BF(i0,i1,WR,WI) { f32x2 tt = cmul(v[i1], (f32x2){(WR),(WI)}); \
    f32x2 a0 = v[i0]; v[i0] = a0 + tt; v[i1] = a0 - tt; }
#define BF1(i0,i1) { f32x2 tt = v[i1]; \
    f32x2 a0 = v[i0]; v[i0] = a0 + tt; v[i1] = a0 - tt; }
#define BFI(i0,i1) { f32x2 b1 = v[i1]; f32x2 tt = (f32x2){-Sf * b1.y, Sf * b1.x}; \
    f32x2 a0 = v[i0]; v[i0] = a0 + tt; v[i1] = a0 - tt; }
    BF1(0,1)  BF1(2,3)  BF1(4,5)   BF1(6,7)  BF1(8,9)  BF1(10,11) BF1(12,13) BF1(14,15)
    BF1(0,2)  BFI(1,3)  BF1(4,6)   BFI(5,7)  BF1(8,10) BFI(9,11)  BF1(12,14) BFI(13,15)
    BF1(0,4)  BF(1,5,C2,Sf*C2) BFI(2,6)  BF(3,7,-C2,Sf*C2)
    BF1(8,12) BF(9,13,C2,Sf*C2) BFI(10,14) BF(11,15,-C2,Sf*C2)
    BF1(0,8)  BF(1,9,C1,Sf*C3)  BF(2,10,C2,Sf*C2)  BF(3,11,C3,Sf*C1)
    BFI(4,12) BF(5,13,-C3,Sf*C1) BF(6,14,-C2,Sf*C2) BF(7,15,-C1,Sf*C3)
#undef BF
#undef BF1
#undef BFI
}

// v[u] *= w1^u, u=1..15 — SERIAL chain (2 live regs; latency hidden by 8 waves/EU)
__device__ __forceinline__ void twiddle16_w(f32x2* v, f32x2 w1) {
    f32x2 w = w1;
    v[1] = cmul(v[1], w);
    #pragma unroll
    for (int u = 2; u < 16; ++u) { w = cmul(w, w1); v[u] = cmul(v[u], w); }
}
__device__ __forceinline__ void twiddle16(f32x2* v, float ang) {
    float sn, cs;
    __sincosf(ang, &sn, &cs);
    twiddle16_w(v, (f32x2){cs, sn});
}

__global__ __launch_bounds__(BT, 8)   // 8 waves/EU -> VGPR cap 64; 4 blocks/CU (LDS 33KB)
void cbp_fused_kernel(const float* __restrict__ x, const float* __restrict__ y,
                      const int* __restrict__ h1, const int* __restrict__ h2,
                      const float* __restrict__ s1, const float* __restrict__ s2,
                      float* __restrict__ out) {
    __shared__ unsigned hz[8448];      // half2-packed complex, pad i+(i>>5); 33792 B
    const int tid = threadIdx.x;
    const int b   = blockIdx.x;

    // hoisted global loads (hide under zero phase)
    float4 xv  = ((const float4*)(x + (size_t)b * D_IN))[tid];
    float4 yv  = ((const float4*)(y + (size_t)b * D_IN))[tid];
    int4   h1v = ((const int4*)h1)[tid];
    int4   h2v = ((const int4*)h2)[tid];
    float4 s1v = ((const float4*)s1)[tid];
    float4 s2v = ((const float4*)s2)[tid];

    // ---- zero ALL 2112 uint4 slots ----
    {
        uint4* z4 = (uint4*)hz;
        z4[tid]        = (uint4){0u, 0u, 0u, 0u};
        z4[tid + 512]  = (uint4){0u, 0u, 0u, 0u};
        z4[tid + 1024] = (uint4){0u, 0u, 0u, 0u};
        z4[tid + 1536] = (uint4){0u, 0u, 0u, 0u};
        if (tid < 64) z4[tid + 2048] = (uint4){0u, 0u, 0u, 0u};
    }
    __syncthreads();

    // ---- count sketch: z = xs + i*ys (fp16 CAS adds) ----
    atomAddH<0>(&hz[h1v.x + (h1v.x >> 5)], xv.x * s1v.x);
    atomAddH<0>(&hz[h1v.y + (h1v.y >> 5)], xv.y * s1v.y);
    atomAddH<0>(&hz[h1v.z + (h1v.z >> 5)], xv.z * s1v.z);
    atomAddH<0>(&hz[h1v.w + (h1v.w >> 5)], xv.w * s1v.w);
    atomAddH<1>(&hz[h2v.x + (h2v.x >> 5)], yv.x * s2v.x);
    atomAddH<1>(&hz[h2v.y + (h2v.y >> 5)], yv.y * s2v.y);
    atomAddH<1>(&hz[h2v.z + (h2v.z >> 5)], yv.z * s2v.z);
    atomAddH<1>(&hz[h2v.w + (h2v.w >> 5)], yv.w * s2v.w);
    __syncthreads();

    f32x2 v[16];
    const int u1 = tid >> 5, m2 = tid & 31;                        // stage-2 digits
    const int g  = tid >> 5, d1 = (tid >> 1) & 15, m3 = tid & 1;   // stage-3 digits

    // ---- fwd S1: radix-16, logical stride 512 (padded 528) ----
    {
        unsigned* zp = &hz[tid + (tid >> 5)];
        #pragma unroll
        for (int r = 0; r < 16; ++r) v[r] = ldH(zp + 528 * r);
        fft16<-1>(v);
        twiddle16(v, (float)tid * (-PI2 / 8192.f));
        #pragma unroll
        for (int u = 0; u < 16; ++u) zp[528 * u] = packH(v[u]);
    }
    __syncthreads();

    // ---- fwd S2: radix-16, logical stride 32 (padded 33) ----
    {
        unsigned* zp = &hz[u1 * 528 + m2];
        #pragma unroll
        for (int r = 0; r < 16; ++r) v[r] = ldH(zp + 33 * r);
        fft16<-1>(v);
        twiddle16(v, (float)m2 * (-PI2 / 512.f));
        #pragma unroll
        for (int u = 0; u < 16; ++u) zp[33 * u] = packH(v[u]);
    }
    __syncthreads();

    // ---- fwd S3: radix-16, stride 2 + radix-2 via lane-pair shfl ----
    // subproblem length 32 -> inter-stage twiddle w1 = e^{-2pi*i*m3/32}
    unsigned* z3p = &hz[g * 528 + d1 * 33 + m3];
    {
        #pragma unroll
        for (int r = 0; r < 16; ++r) v[r] = ldH(z3p + 2 * r);
        fft16<-1>(v);
        f32x2 w1f = m3 ? (f32x2){0.980785280403230449f, -0.195090322016128268f}
                       : (f32x2){1.f, 0.f};
        twiddle16_w(v, w1f);
        const float sgn = m3 ? -1.f : 1.f;
        #pragma unroll
        for (int u = 0; u < 16; ++u) {
            float px = __shfl_xor(v[u].x, 1);
            float py = __shfl_xor(v[u].y, 1);
            v[u] = (f32x2){fmaf(sgn, v[u].x, px), fmaf(sgn, v[u].y, py)};
        }
        #pragma unroll
        for (int u = 0; u < 16; ++u) z3p[2 * u] = packH(v[u]);   // publish for partners
    }
    __syncthreads();

    // ---- Hermitian split + pointwise product, in registers ----
    // v[r] holds k = K0 + 256 r, K0 = g + 16 d1 + 4096 m3
    {
        const int K0 = g + (d1 << 4) + (m3 << 12);
        const int e0 = (FFT_N - K0) & 255;
        const int C  = (FFT_N - K0 - e0) >> 8;
        const unsigned* zb = &hz[(e0 & 15) * 528 + (e0 >> 4) * 33];
        #pragma unroll
        for (int r = 0; r < 16; ++r) {
            const int c = C - r;
            f32x2 z2 = ldH(zb + ((c & 15) << 1) + (c >> 4));
            if (r == 0) { if (K0 == 0) z2 = v[0]; }   // k=0 singleton (tid 0 only)
            f32x2 X = v[r] + (f32x2){ z2.x, -z2.y};               // (2ReX, 2ImX)
            f32x2 Y = (f32x2){v[r].y, -v[r].x} + (f32x2){z2.y, z2.x};  // (2ReY, 2ImY)
            v[r] = cmul(X, Y);                                    // 4*X*Y
        }
    }

    // ---- inverse A (regs): radix-2 shfl, conj twiddle, fft16<+1> ----
    {
        const float sgn = m3 ? -1.f : 1.f;
        #pragma unroll
        for (int u = 0; u < 16; ++u) {
            float px = __shfl_xor(v[u].x, 1);
            float py = __shfl_xor(v[u].y, 1);
            v[u] = (f32x2){fmaf(sgn, v[u].x, px), fmaf(sgn, v[u].y, py)};
        }
        f32x2 w1i = m3 ? (f32x2){0.980785280403230449f, 0.195090322016128268f}
                       : (f32x2){1.f, 0.f};
        twiddle16_w(v, w1i);
        fft16<1>(v);
    }
    __syncthreads();                   // all partner reads done before overwrite
    {
        #pragma unroll
        for (int r = 0; r < 16; ++r) z3p[2 * r] = packH(v[r] * 0.03125f);  // *2^-5
    }
    __syncthreads();

    // ---- inverse B: stride 33 ----
    {
        unsigned* zp = &hz[u1 * 528 + m2];
        #pragma unroll
        for (int u = 0; u < 16; ++u) v[u] = ldH(zp + 33 * u);
        twiddle16(v, (float)m2 * (PI2 / 512.f));
        fft16<1>(v);
        #pragma unroll
        for (int r = 0; r < 16; ++r) zp[33 * r] = packH(v[r] * 0.03125f);  // *2^-5
    }
    __syncthreads();

    // ---- inverse C: stride 528 + coalesced global write of real part ----
    {
        unsigned* zp = &hz[tid + (tid >> 5)];
        #pragma unroll
        for (int u = 0; u < 16; ++u) v[u] = ldH(zp + 528 * u);
        twiddle16(v, (float)tid * (PI2 / 8192.f));
        fft16<1>(v);
        float* orow = out + (size_t)b * FFT_N;
        // remaining scale: 2^-5 (total 2^-15 = 1/(4*8192))
        #pragma unroll
        for (int r = 0; r < 16; ++r) orow[tid + (r << 9)] = v[r].x * 0.03125f;
    }
}

extern "C" void kernel_launch(void* const* d_in, const int* in_sizes, int n_in,
                              void* d_out, int out_size, void* d_ws, size_t ws_size,
                              hipStream_t stream) {
    const float* x  = (const float*)d_in[0];
    const float* y  = (const float*)d_in[1];
    const int*   h1 = (const int*)d_in[2];
    const int*   h2 = (const int*)d_in[3];
    const float* s1 = (const float*)d_in[4];
    const float* s2 = (const float*)d_in[5];
    float* out = (float*)d_out;

    const int B = in_sizes[0] / D_IN;   // 4096 rows
    cbp_fused_kernel<<<B, BT, 0, stream>>>(x, y, h1, h2, s1, s2, out);
}

// Round 11
// 130.425 us; speedup vs baseline: 1.1445x; 1.0279x over previous
//
#include <hip/hip_runtime.h>

#define FFT_N 8192
#define BT    512
#define D_IN  2048
#define PI2   6.28318530717958647692f

typedef float    f32x2 __attribute__((ext_vector_type(2)));
typedef _Float16 f16x2 __attribute__((ext_vector_type(2)));

// ---- packed-fp16 LDS helpers (compute stays fp32 in regs) ----
__device__ __forceinline__ f32x2 ldH(const unsigned* p) {
    f16x2 h = __builtin_bit_cast(f16x2, *p);
    return (f32x2){(float)h.x, (float)h.y};
}
__device__ __forceinline__ unsigned packH(f32x2 v) {   // v_cvt_pkrtz_f16_f32: 1 inst
    auto h = __builtin_amdgcn_cvt_pkrtz(v.x, v.y);     // native __fp16 vec2 type
    return __builtin_bit_cast(unsigned, h);
}
template<int HI>
__device__ __forceinline__ void atomAddH(unsigned* p, float val) {
    unsigned old = *p;
    while (true) {
        f16x2 h = __builtin_bit_cast(f16x2, old);
        if (HI) h.y += (_Float16)val; else h.x += (_Float16)val;
        unsigned nv = __builtin_bit_cast(unsigned, h);
        unsigned got = atomicCAS(p, old, nv);
        if (got == old) break;
        old = got;
    }
}

// plain-C complex multiply: compiler folds into pk ops where it can (round-4/8 proven)
__device__ __forceinline__ f32x2 cmul(f32x2 a, f32x2 b) {
    f32x2 q = (f32x2){-a.y, a.y} * (f32x2){b.y, b.x};
    return (f32x2){a.x, a.x} * b + q;
}

// 16-point DFT, natural in -> natural out, kernel e^{S*2pi*i*ru/16}, unnormalized.
template<int S>
__device__ __forceinline__ void fft16(f32x2* v) {
    const float C1 = 0.923879532511286756f;   // cos(pi/8)
    const float C2 = 0.707106781186547524f;   // cos(pi/4)
    const float C3 = 0.382683432365089772f;   // sin(pi/8)
    const float Sf = (float)S;
    f32x2 t;
#define SW(a,b) t = v[a]; v[a] = v[b]; v[b] = t;
    SW(1,8) SW(2,4) SW(3,12) SW(5,10) SW(7,14) SW(11,13)
#undef SW
#define BF(i0,i1,WR,WI) { f32x2 tt = cmul(v[i1], (f32x2){(WR),(WI)}); \
    f32x2 a0 = v[i0]; v[i0] = a0 + tt; v[i1] = a0 - tt; }
#define BF1(i0,i1) { f32x2 tt = v[i1]; \
    f32x2 a0 = v[i0]; v[i0] = a0 + tt; v[i1] = a0 - tt; }
#define BFI(i0,i1) { f32x2 b1 = v[i1]; f32x2 tt = (f32x2){-Sf * b1.y, Sf * b1.x}; \
    f32x2 a0 = v[i0]; v[i0] = a0 + tt; v[i1] = a0 - tt; }
    BF1(0,1)  BF1(2,3)  BF1(4,5)   BF1(6,7)  BF1(8,9)  BF1(10,11) BF1(12,13) BF1(14,15)
    BF1(0,2)  BFI(1,3)  BF1(4,6)   BFI(5,7)  BF1(8,10) BFI(9,11)  BF1(12,14) BFI(13,15)
    BF1(0,4)  BF(1,5,C2,Sf*C2) BFI(2,6)  BF(3,7,-C2,Sf*C2)
    BF1(8,12) BF(9,13,C2,Sf*C2) BFI(10,14) BF(11,15,-C2,Sf*C2)
    BF1(0,8)  BF(1,9,C1,Sf*C3)  BF(2,10,C2,Sf*C2)  BF(3,11,C3,Sf*C1)
    BFI(4,12) BF(5,13,-C3,Sf*C1) BF(6,14,-C2,Sf*C2) BF(7,15,-C1,Sf*C3)
#undef BF
#undef BF1
#undef BFI
}

// v[u] *= w1^u, u=1..15 — serial chain, 2 live regs
__device__ __forceinline__ void twiddle16_w(f32x2* v, f32x2 w1) {
    f32x2 w = w1;
    v[1] = cmul(v[1], w);
    #pragma unroll
    for (int u = 2; u < 16; ++u) { w = cmul(w, w1); v[u] = cmul(v[u], w); }
}
__device__ __forceinline__ void twiddle16(f32x2* v, float ang) {
    float sn, cs;
    __sincosf(ang, &sn, &cs);
    twiddle16_w(v, (f32x2){cs, sn});
}

__global__ __launch_bounds__(BT, 6)   // VGPR cap ~84: kill the spill seen at cap 64
void cbp_fused_kernel(const float* __restrict__ x, const float* __restrict__ y,
                      const int* __restrict__ h1, const int* __restrict__ h2,
                      const float* __restrict__ s1, const float* __restrict__ s2,
                      float* __restrict__ out) {
    __shared__ unsigned hz[8448];      // half2-packed complex, pad i+(i>>5); 33792 B
    const int tid = threadIdx.x;
    const int b   = blockIdx.x;

    // hoisted global loads (hide under zero phase)
    float4 xv  = ((const float4*)(x + (size_t)b * D_IN))[tid];
    float4 yv  = ((const float4*)(y + (size_t)b * D_IN))[tid];
    int4   h1v = ((const int4*)h1)[tid];
    int4   h2v = ((const int4*)h2)[tid];
    float4 s1v = ((const float4*)s1)[tid];
    float4 s2v = ((const float4*)s2)[tid];

    // ---- zero ALL 2112 uint4 slots ----
    {
        uint4* z4 = (uint4*)hz;
        z4[tid]        = (uint4){0u, 0u, 0u, 0u};
        z4[tid + 512]  = (uint4){0u, 0u, 0u, 0u};
        z4[tid + 1024] = (uint4){0u, 0u, 0u, 0u};
        z4[tid + 1536] = (uint4){0u, 0u, 0u, 0u};
        if (tid < 64) z4[tid + 2048] = (uint4){0u, 0u, 0u, 0u};
    }
    __syncthreads();

    // ---- count sketch: z = xs + i*ys (fp16 CAS adds) ----
    atomAddH<0>(&hz[h1v.x + (h1v.x >> 5)], xv.x * s1v.x);
    atomAddH<0>(&hz[h1v.y + (h1v.y >> 5)], xv.y * s1v.y);
    atomAddH<0>(&hz[h1v.z + (h1v.z >> 5)], xv.z * s1v.z);
    atomAddH<0>(&hz[h1v.w + (h1v.w >> 5)], xv.w * s1v.w);
    atomAddH<1>(&hz[h2v.x + (h2v.x >> 5)], yv.x * s2v.x);
    atomAddH<1>(&hz[h2v.y + (h2v.y >> 5)], yv.y * s2v.y);
    atomAddH<1>(&hz[h2v.z + (h2v.z >> 5)], yv.z * s2v.z);
    atomAddH<1>(&hz[h2v.w + (h2v.w >> 5)], yv.w * s2v.w);
    __syncthreads();

    f32x2 v[16];
    const int u1 = tid >> 5, m2 = tid & 31;                        // stage-2 digits
    const int g  = tid >> 5, d1 = (tid >> 1) & 15, m3 = tid & 1;   // stage-3 digits

    // ---- fwd S1: radix-16, logical stride 512 (padded 528) ----
    {
        unsigned* zp = &hz[tid + (tid >> 5)];
        #pragma unroll
        for (int r = 0; r < 16; ++r) v[r] = ldH(zp + 528 * r);
        fft16<-1>(v);
        twiddle16(v, (float)tid * (-PI2 / 8192.f));
        #pragma unroll
        for (int u = 0; u < 16; ++u) zp[528 * u] = packH(v[u]);
    }
    __syncthreads();

    // ---- fwd S2: radix-16, logical stride 32 (padded 33) ----
    {
        unsigned* zp = &hz[u1 * 528 + m2];
        #pragma unroll
        for (int r = 0; r < 16; ++r) v[r] = ldH(zp + 33 * r);
        fft16<-1>(v);
        twiddle16(v, (float)m2 * (-PI2 / 512.f));
        #pragma unroll
        for (int u = 0; u < 16; ++u) zp[33 * u] = packH(v[u]);
    }
    __syncthreads();

    // ---- fwd S3: radix-16, stride 2 + radix-2 via lane-pair shfl ----
    unsigned* z3p = &hz[g * 528 + d1 * 33 + m3];
    {
        #pragma unroll
        for (int r = 0; r < 16; ++r) v[r] = ldH(z3p + 2 * r);
        fft16<-1>(v);
        f32x2 w1f = m3 ? (f32x2){0.980785280403230449f, -0.195090322016128268f}
                       : (f32x2){1.f, 0.f};
        twiddle16_w(v, w1f);
        const float sgn = m3 ? -1.f : 1.f;
        #pragma unroll
        for (int u = 0; u < 16; ++u) {
            float px = __shfl_xor(v[u].x, 1);
            float py = __shfl_xor(v[u].y, 1);
            v[u] = (f32x2){fmaf(sgn, v[u].x, px), fmaf(sgn, v[u].y, py)};
        }
        #pragma unroll
        for (int u = 0; u < 16; ++u) z3p[2 * u] = packH(v[u]);   // publish for partners
    }
    __syncthreads();

    // ---- Hermitian split + pointwise product, in registers ----
    // v[r] holds k = K0 + 256 r, K0 = g + 16 d1 + 4096 m3
    {
        const int K0 = g + (d1 << 4) + (m3 << 12);
        const int e0 = (FFT_N - K0) & 255;
        const int C  = (FFT_N - K0 - e0) >> 8;
        const unsigned* zb = &hz[(e0 & 15) * 528 + (e0 >> 4) * 33];
        #pragma unroll
        for (int r = 0; r < 16; ++r) {
            const int c = C - r;
            f32x2 z2 = ldH(zb + ((c & 15) << 1) + (c >> 4));
            if (r == 0) { if (K0 == 0) z2 = v[0]; }   // k=0 singleton (tid 0 only)
            f32x2 X = v[r] + (f32x2){ z2.x, -z2.y};               // (2ReX, 2ImX)
            f32x2 Y = (f32x2){v[r].y, -v[r].x} + (f32x2){z2.y, z2.x};  // (2ReY, 2ImY)
            v[r] = cmul(X, Y);                                    // 4*X*Y
        }
    }

    // ---- inverse A (regs): radix-2 shfl, conj twiddle, fft16<+1> ----
    {
        const float sgn = m3 ? -1.f : 1.f;
        #pragma unroll
        for (int u = 0; u < 16; ++u) {
            float px = __shfl_xor(v[u].x, 1);
            float py = __shfl_xor(v[u].y, 1);
            v[u] = (f32x2){fmaf(sgn, v[u].x, px), fmaf(sgn, v[u].y, py)};
        }
        f32x2 w1i = m3 ? (f32x2){0.980785280403230449f, 0.195090322016128268f}
                       : (f32x2){1.f, 0.f};
        twiddle16_w(v, w1i);
        fft16<1>(v);
    }
    __syncthreads();                   // all partner reads done before overwrite
    {
        #pragma unroll
        for (int r = 0; r < 16; ++r) z3p[2 * r] = packH(v[r] * 0.03125f);  // *2^-5
    }
    __syncthreads();

    // ---- inverse B: stride 33 ----
    {
        unsigned* zp = &hz[u1 * 528 + m2];
        #pragma unroll
        for (int u = 0; u < 16; ++u) v[u] = ldH(zp + 33 * u);
        twiddle16(v, (float)m2 * (PI2 / 512.f));
        fft16<1>(v);
        #pragma unroll
        for (int r = 0; r < 16; ++r) zp[33 * r] = packH(v[r] * 0.03125f);  // *2^-5
    }
    __syncthreads();

    // ---- inverse C: stride 528 + coalesced global write of real part ----
    {
        unsigned* zp = &hz[tid + (tid >> 5)];
        #pragma unroll
        for (int u = 0; u < 16; ++u) v[u] = ldH(zp + 528 * u);
        twiddle16(v, (float)tid * (PI2 / 8192.f));
        fft16<1>(v);
        float* orow = out + (size_t)b * FFT_N;
        // remaining scale: 2^-5 (total 2^-15 = 1/(4*8192))
        #pragma unroll
        for (int r = 0; r < 16; ++r) orow[tid + (r << 9)] = v[r].x * 0.03125f;
    }
}

extern "C" void kernel_launch(void* const* d_in, const int* in_sizes, int n_in,
                              void* d_out, int out_size, void* d_ws, size_t ws_size,
                              hipStream_t stream) {
    const float* x  = (const float*)d_in[0];
    const float* y  = (const float*)d_in[1];
    const int*   h1 = (const int*)d_in[2];
    const int*   h2 = (const int*)d_in[3];
    const float* s1 = (const float*)d_in[4];
    const float* s2 = (const float*)d_in[5];
    float* out = (float*)d_out;

    const int B = in_sizes[0] / D_IN;   // 4096 rows
    cbp_fused_kernel<<<B, BT, 0, stream>>>(x, y, h1, h2, s1, s2, out);
}